// Round 3
// baseline (721.174 us; speedup 1.0000x reference)
//
#include <hip/hip_runtime.h>

// Problem constants
#define BB    16
#define CIN   32
#define LEN   1024
#define TT    64
#define COUT  64
#define KK    3

// Tiling: wave = co-group (8 co); lanes = tsub[2b] x l[4b]; chunk = 16 t.
#define TL       16                  // l per block -> grid 64x16 = 1024 blocks
#define HALO     (TL + 2)            // 18 rows incl. conv halo
#define NTHREADS 512                 // 8 waves = 8 co-groups of 8
#define NGRAN    (CIN * HALO * 4)    // 2304 16-B granules / buffer (36864 B)
#define NROUND   (NGRAN / 64)        // 36 wave-rounds per buffer fill

// INVARIANT (bit-exact vs np ref, proven in earlier rounds): per output cell
// the conv sum is ONE sequential fmaf chain, k outer (0..2), ci inner (0..31),
// acc=0; LIF fp32: s=pot+a; p=s*0.9f; spk=(p>=0.25f); pot=spk?0:p.
// OOB halo terms participate as fmaf(0,w,acc) — same as reference's zero-pad.

// Packed weights: wpk2[((g2*3+k)*32+ci)*8 + j] = w[(g2*8+j)][ci][k]
__device__ float wpk2[COUT * CIN * KK];
// Zero page for out-of-range halo rows (never written -> stays 0).
__device__ float zeros_g[64];

__global__ void repack_w(const float* __restrict__ w) {
    const int i = blockIdx.x * 256 + threadIdx.x;      // 6144 total
    if (i < COUT * CIN * KK) {
        const int j  = i & 7;
        const int ci = (i >> 3) & 31;
        const int gk = i >> 8;                         // g2*3 + k
        const int k  = gk % 3;
        const int g2 = gk / 3;
        wpk2[i] = w[((g2 * 8 + j) * CIN + ci) * KK + k];
    }
}

// 16-B async global->LDS (dest = wave-uniform base + lane*16; source per-lane).
#define GLD16(GP, LP) __builtin_amdgcn_global_load_lds(                      \
    (const __attribute__((address_space(1))) void*)(GP),                     \
    (__attribute__((address_space(3))) void*)(LP), 16, 0, 0)

__global__ __launch_bounds__(NTHREADS, 4)
void snn_v6(const float* __restrict__ x, float* __restrict__ out) {
    // LINEAR layout (no swizzle): granule G=(ci*18+row)*4+h at byte G*16.
    // Conv read (fixed k,ci): lanes cover (l+k)*64 + tsub*16 -> contiguous
    // 1 KB per wave-instr, conflict-free full-width ds_read_b128.
    __shared__ float4 xsg[2][NGRAN];         // 73728 B -> 2 blocks/CU

    const int tid  = threadIdx.x;
    const int l    = tid & 15;
    const int tsub = (tid >> 4) & 3;                   // 4-t sub-chunk owner
    const int lane = tid & 63;
    const int wv   = __builtin_amdgcn_readfirstlane(tid >> 6);  // co-group 0..7
    const int l0   = blockIdx.x * TL;
    const int b    = blockIdx.y;
    const int lo   = l0 + l;

    const float* xb   = x + (size_t)b * CIN * LEN * TT;
    float*       outb = out + (size_t)b * COUT * LEN * TT;
    // wave-uniform scalar base -> weight reads compile to s_load; SGPR fma src
    const float* wgb  = wpk2 + wv * (KK * CIN * 8);

    // staging sources: wave wv fills rounds r = wv + 8m (granules r*64+lane)
    const float* src[5];
    #pragma unroll
    for (int m = 0; m < 5; ++m) {
        const float* p = zeros_g;
        const int r = wv + 8 * m;
        if (r < NROUND) {
            const int G   = r * 64 + lane;
            const int ci  = G / (HALO * 4);
            const int rem = G - ci * (HALO * 4);
            const int row = rem >> 2;
            const int h   = rem & 3;                   // 16-B sub of 64-B row
            const int lg  = l0 - 1 + row;
            if (lg >= 0 && lg < LEN)
                p = xb + ((size_t)ci * LEN + lg) * TT + h * 4;
        }
        src[m] = p;
    }

    auto issue = [&](int tc, int buf) {
        char* lb = (char*)&xsg[buf][0];
        #pragma unroll
        for (int m = 0; m < 4; ++m)
            GLD16(src[m] + tc * 16, lb + (wv + 8 * m) * 1024);
        if (wv < 4)
            GLD16(src[4] + tc * 16, lb + (wv + 32) * 1024);
    };

    float pot[8];
    #pragma unroll
    for (int j = 0; j < 8; ++j) pot[j] = 0.f;
    unsigned nibp = 0;                      // previous chunk's spike nibbles

    issue(0, 0);                            // prologue: chunk 0 -> buf 0

    #pragma unroll 2
    for (int tc = 0; tc < 4; ++tc) {        // chunk = 16 t (full 64-B rows)
        const int cur = tc & 1;
        // barrier: drains our gld_lds (buf[cur] ready) + all waves done
        // reading buf[cur^1] -> safe to refill it.
        __syncthreads();
        if (tc + 1 < 4) issue(tc + 1, cur ^ 1);

        const char* xsv = (const char*)&xsg[cur][0] + tsub * 16;

        // ---- conv: EXACT chain order k outer, ci inner, sequential fmaf
        float acc[8][4];
        #pragma unroll
        for (int j = 0; j < 8; ++j)
            #pragma unroll
            for (int i = 0; i < 4; ++i) acc[j][i] = 0.f;

        #pragma unroll
        for (int k = 0; k < KK; ++k) {
            const char*  bk = xsv + (l + k) * 64;
            const float* wk = wgb + k * (CIN * 8);
            #pragma unroll 1
            for (int cic = 0; cic < 4; ++cic) {
                #pragma unroll
                for (int c8 = 0; c8 < 8; ++c8) {
                    const int ci = cic * 8 + c8;
                    const float4 xr = *(const float4*)(bk + ci * 1152);
                    const float* wp = wk + ci * 8;
                    #pragma unroll
                    for (int j = 0; j < 8; ++j) {
                        const float wj = wp[j];          // SGPR operand
                        acc[j][0] = fmaf(xr.x, wj, acc[j][0]);
                        acc[j][1] = fmaf(xr.y, wj, acc[j][1]);
                        acc[j][2] = fmaf(xr.z, wj, acc[j][2]);
                        acc[j][3] = fmaf(xr.w, wj, acc[j][3]);
                    }
                }
            }
        }

        // ---- LIF: 4 wave-synchronous tsub-phases (t ascending); pot handoff
        // via shuffle from the lane owning the previous 4-t sub-chunk.
        unsigned nibc = 0;
        #pragma unroll
        for (int ph = 0; ph < 4; ++ph) {
            const int srcl = (((ph + 3) & 3) << 4) | l;
            #pragma unroll
            for (int j = 0; j < 8; ++j) {
                const float pin = __shfl(pot[j], srcl, 64);  // all lanes active
                if (tsub == ph) {
                    float pp = pin;
                    unsigned sb = 0;
                    #pragma unroll
                    for (int i = 0; i < 4; ++i) {
                        const float s  = pp + acc[j][i];
                        const float p  = s * 0.9f;
                        const bool  sp = (p >= 0.25f);
                        sb |= sp ? (1u << i) : 0u;
                        pp = sp ? 0.f : p;
                    }
                    pot[j] = pp;
                    nibc |= sb << (j * 4);
                }
            }
        }

        // ---- stores: at odd tc write the chunk pair -> 128 B per (co,l),
        // wave-instr covers l x tsub = contiguous full lines.
        if (cur) {
            #pragma unroll
            for (int j = 0; j < 8; ++j) {
                float* dst = outb + ((size_t)(wv * 8 + j) * LEN + lo) * TT
                           + (tc - 1) * 16 + tsub * 4;
                const unsigned n0 = (nibp >> (j * 4)) & 0xFu;
                const unsigned n1 = (nibc >> (j * 4)) & 0xFu;
                *(float4*)dst = make_float4(n0 & 1u ? 1.f : 0.f,
                                            n0 & 2u ? 1.f : 0.f,
                                            n0 & 4u ? 1.f : 0.f,
                                            n0 & 8u ? 1.f : 0.f);
                *(float4*)(dst + 16) = make_float4(n1 & 1u ? 1.f : 0.f,
                                                   n1 & 2u ? 1.f : 0.f,
                                                   n1 & 4u ? 1.f : 0.f,
                                                   n1 & 8u ? 1.f : 0.f);
            }
        } else {
            nibp = nibc;
        }
    }
}

extern "C" void kernel_launch(void* const* d_in, const int* in_sizes, int n_in,
                              void* d_out, int out_size, void* d_ws, size_t ws_size,
                              hipStream_t stream) {
    const float* x = (const float*)d_in[0];   // (16, 32, 1024, 64) fp32
    const float* w = (const float*)d_in[1];   // (64, 32, 3) fp32
    float* out = (float*)d_out;               // (16, 64, 1024, 64) fp32
    (void)d_ws; (void)ws_size; (void)in_sizes; (void)n_in; (void)out_size;

    hipLaunchKernelGGL(repack_w, dim3(24), dim3(256), 0, stream, w);
    hipLaunchKernelGGL(snn_v6, dim3(LEN / TL, BB), dim3(NTHREADS),
                       0, stream, x, out);
}